// Round 15
// baseline (38.472 us; speedup 1.0000x reference)
//
#include <hip/hip_runtime.h>
#include <hip/hip_cooperative_groups.h>
namespace cg = cooperative_groups;

#define NBLK 256
// float offsets into ws
#define WS_LP   0        // lpart [4][256]
#define WS_KQ   1024     // kq 1024
#define WS_C4   2048     // c4 4 (pad 64)
#define WS_CTXP 2112     // ctxp [256][256]

__device__ __forceinline__ float dot4(float4 a, float4 b) {
  return a.x * b.x + a.y * b.y + a.z * b.z + a.w * b.w;
}

// ---- Phase A (blocks 0..15): q_h redundant per (h,qt), kq quarter, c4 (verified R8/R14) ----
__device__ __forceinline__ void phaseA_kq(const float* __restrict__ x, const float* __restrict__ W,
                                          const float* __restrict__ inb, float* __restrict__ kq,
                                          float* __restrict__ c4, float* sh, int bid, int t) {
  float* xs = sh;          // 256
  float* qls = sh + 256;   // 64
  float* red = sh + 320;   // 512
  const int lane = t & 63, w = t >> 6;
  const int h = bid >> 2, qt = bid & 3;
  if (t < 256) xs[t] = x[t];
  __syncthreads();
  const float4 xv = *(const float4*)&xs[lane * 4];
#pragma unroll
  for (int k = 0; k < 8; ++k) {
    const int eloc = w * 8 + k;
    const int row = h * 64 + eloc;
    float4 wv = *(const float4*)&W[(size_t)row * 256 + lane * 4];
    float p = dot4(wv, xv);
#pragma unroll
    for (int m = 1; m < 64; m <<= 1) p += __shfl_xor(p, m);
    if (lane == 0) qls[eloc] = p + inb[row];
  }
  __syncthreads();
  const int cl = t & 63, ds = t >> 6;
  float acc = 0.f;
#pragma unroll
  for (int d2 = 0; d2 < 8; ++d2) {
    const int d = ds * 8 + d2;
    acc += W[(size_t)(256 + h * 64 + d) * 256 + qt * 64 + cl] * qls[d];
  }
  red[ds * 64 + cl] = acc;
  __syncthreads();
  if (ds == 0) {
    float s = 0.f;
#pragma unroll
    for (int i = 0; i < 8; ++i) s += red[i * 64 + cl];
    kq[h * 256 + qt * 64 + cl] = s;
  }
  if (qt == 0 && t < 64) {
    float v = qls[t] * inb[256 + h * 64 + t];
#pragma unroll
    for (int m = 1; m < 64; m <<= 1) v += __shfl_xor(v, m);
    if (t == 0) c4[h] = v;
  }
}

// ---- Phase B: scores + exp + Y + ctx-partial (ctxp[b] = Wv.Y_b), no max-sub (verified R13/R14) ----
__device__ __forceinline__ float bscore(float4 xv, float4 kq0, float4 kq1, float4 kq2,
                                        float4 kq3, float c4v, int lane) {
  float p0 = dot4(xv, kq0), p1 = dot4(xv, kq1), p2 = dot4(xv, kq2), p3 = dot4(xv, kq3);
  const bool b1 = (lane & 2) != 0;
  float keep0 = b1 ? p2 : p0, send0 = b1 ? p0 : p2;
  keep0 += __shfl_xor(send0, 2);
  float keep1 = b1 ? p3 : p1, send1 = b1 ? p1 : p3;
  keep1 += __shfl_xor(send1, 2);
  const bool b0 = (lane & 1) != 0;
  float vv = b0 ? keep1 : keep0, sv = b0 ? keep0 : keep1;
  vv += __shfl_xor(sv, 1);
  vv += __shfl_xor(vv, 4);
  vv += __shfl_xor(vv, 8);
  vv += __shfl_xor(vv, 16);
  vv += __shfl_xor(vv, 32);
  return (vv + c4v) * 0.125f;
}

__device__ __forceinline__ void phaseB_core(const float4* xvA, const float4* xvB,
                                            const float* __restrict__ kq, const float* __restrict__ c4,
                                            const float* __restrict__ W,
                                            float* __restrict__ lpart, float* __restrict__ ctxp,
                                            float* yls, int bid, int t) {
  float* sll = yls + 8192;  // 32
  const int lane = t & 63, w = t >> 6;
  const int hme = lane & 3;
  const float4 kq0 = *(const float4*)&kq[0 * 256 + lane * 4];
  const float4 kq1 = *(const float4*)&kq[1 * 256 + lane * 4];
  const float4 kq2 = *(const float4*)&kq[2 * 256 + lane * 4];
  const float4 kq3 = *(const float4*)&kq[3 * 256 + lane * 4];
  const float c4v = c4[hme];

  float vA[8], vB[8];
#pragma unroll
  for (int r = 0; r < 8; ++r) vA[r] = bscore(xvA[r], kq0, kq1, kq2, kq3, c4v, lane);
#pragma unroll
  for (int r = 0; r < 8; ++r) vB[r] = bscore(xvB[r], kq0, kq1, kq2, kq3, c4v, lane);

  float l = 0.f;
  float4 a[4];
#pragma unroll
  for (int k = 0; k < 4; ++k) a[k] = (float4){0.f, 0.f, 0.f, 0.f};
#pragma unroll
  for (int r = 0; r < 8; ++r) {
    const float e0 = __expf(vA[r]);
    l += e0;
    const float e1 = __shfl_xor(e0, 1);
    const float e2 = __shfl_xor(e0, 2);
    const float e3 = __shfl_xor(e0, 3);
    a[0].x += e0 * xvA[r].x; a[0].y += e0 * xvA[r].y; a[0].z += e0 * xvA[r].z; a[0].w += e0 * xvA[r].w;
    a[1].x += e1 * xvA[r].x; a[1].y += e1 * xvA[r].y; a[1].z += e1 * xvA[r].z; a[1].w += e1 * xvA[r].w;
    a[2].x += e2 * xvA[r].x; a[2].y += e2 * xvA[r].y; a[2].z += e2 * xvA[r].z; a[2].w += e2 * xvA[r].w;
    a[3].x += e3 * xvA[r].x; a[3].y += e3 * xvA[r].y; a[3].z += e3 * xvA[r].z; a[3].w += e3 * xvA[r].w;
  }
#pragma unroll
  for (int r = 0; r < 8; ++r) {
    const float e0 = __expf(vB[r]);
    l += e0;
    const float e1 = __shfl_xor(e0, 1);
    const float e2 = __shfl_xor(e0, 2);
    const float e3 = __shfl_xor(e0, 3);
    a[0].x += e0 * xvB[r].x; a[0].y += e0 * xvB[r].y; a[0].z += e0 * xvB[r].z; a[0].w += e0 * xvB[r].w;
    a[1].x += e1 * xvB[r].x; a[1].y += e1 * xvB[r].y; a[1].z += e1 * xvB[r].z; a[1].w += e1 * xvB[r].w;
    a[2].x += e2 * xvB[r].x; a[2].y += e2 * xvB[r].y; a[2].z += e2 * xvB[r].z; a[2].w += e2 * xvB[r].w;
    a[3].x += e3 * xvB[r].x; a[3].y += e3 * xvB[r].y; a[3].z += e3 * xvB[r].z; a[3].w += e3 * xvB[r].w;
  }

  __syncthreads();  // sh reuse after phase A
  if (lane < 4) sll[w * 4 + lane] = l;  // hme==lane for lane<4
#pragma unroll
  for (int k = 0; k < 4; ++k) {
    const int h = hme ^ k;
    *(float4*)&yls[w * 1024 + h * 256 + lane * 4] = a[k];
  }
  __syncthreads();

  if (t < 4) {
    float lb = 0.f;
#pragma unroll
    for (int i = 0; i < 8; ++i) lb += sll[i * 4 + t];
    lpart[t * NBLK + bid] = lb;
  }
  // assemble block Y into yls[0..1023] (each o owned by exactly one thread)
#pragma unroll
  for (int o = t; o < 1024; o += 512) {
    float s = 0.f;
#pragma unroll
    for (int i = 0; i < 8; ++i) s += yls[i * 1024 + o];
    yls[o] = s;
  }
  __syncthreads();

  // ctxp[bid][i] = Wv[i] . Y_{h(i)}   (wave w owns i in [w*32, w*32+32), 4-row batches)
  float* co = &ctxp[(size_t)bid * 256];
  for (int k = 0; k < 32; k += 4) {
    float p[4];
#pragma unroll
    for (int j = 0; j < 4; ++j) {
      const int ii = w * 32 + k + j;
      float4 wv = *(const float4*)&W[(size_t)(512 + ii) * 256 + lane * 4];
      float4 yy = *(const float4*)&yls[(ii >> 6) * 256 + lane * 4];
      p[j] = dot4(wv, yy);
    }
#pragma unroll
    for (int m = 1; m < 64; m <<= 1) {
#pragma unroll
      for (int j = 0; j < 4; ++j) p[j] += __shfl_xor(p[j], m);
    }
    if (lane == 0) {
#pragma unroll
      for (int j = 0; j < 4; ++j) co[w * 32 + k + j] = p[j];
    }
  }
}

// ---- Phase F (16 blocks, 16 outputs each): l-reduce, ctx = sum(ctxp)/l + bv, out = Wout.ctx + bout ----
__device__ __forceinline__ void phaseF(const float* __restrict__ inb, const float* __restrict__ Wout,
                                       const float* __restrict__ bout, const float* __restrict__ lpart,
                                       const float* __restrict__ ctxp, float* __restrict__ out,
                                       float* sh, int bid, int t) {
  float* linv = sh;         // 4 (pad 16)
  float* sctx = sh + 16;    // 2*256
  float* ctxls = sh + 528;  // 256
  const int lane = t & 63, w = t >> 6;
  if (w < 4) {
    float s = 0.f;
#pragma unroll
    for (int j = 0; j < 4; ++j) s += lpart[w * 256 + j * 64 + lane];
#pragma unroll
    for (int m = 1; m < 64; m <<= 1) s += __shfl_xor(s, m);
    if (lane == 0) linv[w] = 1.0f / s;
  }
  // sum ctxp over 256 blocks (split across 2 half-ranges for parallelism)
  const int i = t & 255, part = t >> 8;
  {
    float s = 0.f;
    const float* cp = ctxp + (size_t)part * 128 * 256 + i;
#pragma unroll 8
    for (int b = 0; b < 128; ++b) s += cp[(size_t)b * 256];
    sctx[part * 256 + i] = s;
  }
  __syncthreads();
  if (t < 256) ctxls[t] = (sctx[t] + sctx[256 + t]) * linv[t >> 6] + inb[512 + t];
  __syncthreads();
  const float4 cv = *(const float4*)&ctxls[lane * 4];
#pragma unroll
  for (int k = 0; k < 2; ++k) {
    const int e = bid * 16 + w * 2 + k;
    float4 wv = *(const float4*)&Wout[(size_t)e * 256 + lane * 4];
    float p = dot4(wv, cv);
#pragma unroll
    for (int m = 1; m < 64; m <<= 1) p += __shfl_xor(p, m);
    if (lane == 0) out[e] = p + bout[e];
  }
}

// ---- Cooperative all-in-one: TWO grid.syncs ----
__global__ void __launch_bounds__(512, 1) mha_coop(const float* __restrict__ x,
                                                   const float* __restrict__ W,
                                                   const float* __restrict__ inb,
                                                   const float* __restrict__ Wout,
                                                   const float* __restrict__ bout,
                                                   float* __restrict__ out,
                                                   float* __restrict__ ws) {
  __shared__ __align__(16) float sh[8224];
  const int t = threadIdx.x, bid = blockIdx.x;
  const int lane = t & 63, w = t >> 6;
  cg::grid_group grid = cg::this_grid();

  const int r0 = bid * 128 + w * 16;
  float4 xvA[8], xvB[8];

  if (bid >= 16) {
#pragma unroll
    for (int r = 0; r < 8; ++r)
      xvA[r] = *(const float4*)&x[(size_t)(r0 + r) * 256 + lane * 4];
#pragma unroll
    for (int r = 0; r < 8; ++r)
      xvB[r] = *(const float4*)&x[(size_t)(r0 + 8 + r) * 256 + lane * 4];
  }

  if (bid < 16) {
    phaseA_kq(x, W, inb, ws + WS_KQ, ws + WS_C4, sh, bid, t);
#pragma unroll
    for (int r = 0; r < 8; ++r)
      xvA[r] = *(const float4*)&x[(size_t)(r0 + r) * 256 + lane * 4];
#pragma unroll
    for (int r = 0; r < 8; ++r)
      xvB[r] = *(const float4*)&x[(size_t)(r0 + 8 + r) * 256 + lane * 4];
  }

  grid.sync();  // kq/c4 ready
  phaseB_core(xvA, xvB, ws + WS_KQ, ws + WS_C4, W, ws + WS_LP, ws + WS_CTXP, sh, bid, t);
  grid.sync();  // lpart/ctxp ready
  if (bid < 16) phaseF(inb, Wout, bout, ws + WS_LP, ws + WS_CTXP, out, sh, bid, t);
}

// ---- Fallback chain (no coop): 3 launches, stream-ordered ----
__global__ void __launch_bounds__(512) fb_A(const float* __restrict__ x, const float* __restrict__ W,
                                            const float* __restrict__ inb, float* __restrict__ ws) {
  __shared__ __align__(16) float sh[832];
  phaseA_kq(x, W, inb, ws + WS_KQ, ws + WS_C4, sh, blockIdx.x, threadIdx.x);
}
__global__ void __launch_bounds__(512) fb_B(const float* __restrict__ x, const float* __restrict__ W,
                                            float* __restrict__ ws) {
  __shared__ __align__(16) float sh[8224];
  const int bid = blockIdx.x, t = threadIdx.x;
  const int lane = t & 63, w = t >> 6;
  const int r0 = bid * 128 + w * 16;
  float4 xvA[8], xvB[8];
#pragma unroll
  for (int r = 0; r < 8; ++r)
    xvA[r] = *(const float4*)&x[(size_t)(r0 + r) * 256 + lane * 4];
#pragma unroll
  for (int r = 0; r < 8; ++r)
    xvB[r] = *(const float4*)&x[(size_t)(r0 + 8 + r) * 256 + lane * 4];
  phaseB_core(xvA, xvB, ws + WS_KQ, ws + WS_C4, W, ws + WS_LP, ws + WS_CTXP, sh, bid, t);
}
__global__ void __launch_bounds__(512) fb_F(const float* __restrict__ inb, const float* __restrict__ Wout,
                                            const float* __restrict__ bout, float* __restrict__ out,
                                            float* __restrict__ ws) {
  __shared__ __align__(16) float sh[800];
  phaseF(inb, Wout, bout, ws + WS_LP, ws + WS_CTXP, out, sh, blockIdx.x, threadIdx.x);
}

extern "C" void kernel_launch(void* const* d_in, const int* in_sizes, int n_in,
                              void* d_out, int out_size, void* d_ws, size_t ws_size,
                              hipStream_t stream) {
  const float* x = (const float*)d_in[0];
  const float* W = (const float*)d_in[1];
  const float* inb = (const float*)d_in[2];
  const float* Wout = (const float*)d_in[3];
  const float* bout = (const float*)d_in[4];
  float* out = (float*)d_out;
  float* ws = (float*)d_ws;

  int dev = 0;
  (void)hipGetDevice(&dev);
  int coopAttr = 0, ncu = 0, occ = 0;
  bool coop = (hipDeviceGetAttribute(&coopAttr, hipDeviceAttributeCooperativeLaunch, dev) == hipSuccess) &&
              coopAttr != 0;
  coop = coop &&
         (hipDeviceGetAttribute(&ncu, hipDeviceAttributeMultiprocessorCount, dev) == hipSuccess);
  coop = coop &&
         (hipOccupancyMaxActiveBlocksPerMultiprocessor(&occ, mha_coop, 512, 0) == hipSuccess);
  coop = coop && (occ * ncu >= NBLK);

  if (coop) {
    void* args[] = {(void*)&x, (void*)&W, (void*)&inb, (void*)&Wout,
                    (void*)&bout, (void*)&out, (void*)&ws};
    if (hipLaunchCooperativeKernel((const void*)mha_coop, dim3(NBLK), dim3(512),
                                   args, 0, stream) == hipSuccess)
      return;
  }
  fb_A<<<16, 512, 0, stream>>>(x, W, inb, ws);
  fb_B<<<NBLK, 512, 0, stream>>>(x, W, ws);
  fb_F<<<16, 512, 0, stream>>>(inb, Wout, bout, out, ws);
}

// Round 16
// 34.336 us; speedup vs baseline: 1.1205x; 1.1205x over previous
//
#include <hip/hip_runtime.h>
#include <hip/hip_cooperative_groups.h>
namespace cg = cooperative_groups;

#define NBLK 256
#define MAGIC 0x5A5A5A5A
#define SCALE 4194304.0f        // 2^22
#define INV_SCALE 2.38418579e-7f

// float offsets into ws
#define WS_LP   0        // lpart [4][256]
#define WS_KQ   1024     // kq 1024
#define WS_C4   2048     // c4 4 (pad 64)
#define WS_B2   2112     // bias2 256
#define WS_M2   2368     // M2 256*1024
#define WS_YP   264512   // ypart 256*1024
#define WS_ACC  526656   // out_acc: 256 ints padded stride 16 (4096 ints)
#define WS_TK   530752   // ticket (1 int, pad 16)
#define WS_FLA  530768   // flagA 16 ints

__device__ __forceinline__ float dot4(float4 a, float4 b) {
  return a.x * b.x + a.y * b.y + a.z * b.z + a.w * b.w;
}

__device__ __forceinline__ void set_flag(int* slot, int t) {
  __threadfence();
  __syncthreads();
  if (t == 0) __hip_atomic_store(slot, MAGIC, __ATOMIC_RELEASE, __HIP_MEMORY_SCOPE_AGENT);
}
__device__ __forceinline__ void poll_flags(const int* flags, int n, int t) {
  const int idx = t & (n - 1);
  for (;;) {
    int v = __hip_atomic_load((int*)&flags[idx], __ATOMIC_RELAXED, __HIP_MEMORY_SCOPE_AGENT);
    if (__syncthreads_and(v == MAGIC)) break;
    __builtin_amdgcn_s_sleep(2);
  }
  __threadfence();
}

// ---- Phase A (blocks 0..15): q_h redundant per (h,qt), kq quarter, c4 (verified R8/R14) ----
__device__ __forceinline__ void phaseA_kq(const float* __restrict__ x, const float* __restrict__ W,
                                          const float* __restrict__ inb, float* __restrict__ kq,
                                          float* __restrict__ c4, float* sh, int bid, int t) {
  float* xs = sh;          // 256
  float* qls = sh + 256;   // 64
  float* red = sh + 320;   // 512
  const int lane = t & 63, w = t >> 6;
  const int h = bid >> 2, qt = bid & 3;
  if (t < 256) xs[t] = x[t];
  __syncthreads();
  const float4 xv = *(const float4*)&xs[lane * 4];
#pragma unroll
  for (int k = 0; k < 8; ++k) {
    const int eloc = w * 8 + k;
    const int row = h * 64 + eloc;
    float4 wv = *(const float4*)&W[(size_t)row * 256 + lane * 4];
    float p = dot4(wv, xv);
#pragma unroll
    for (int m = 1; m < 64; m <<= 1) p += __shfl_xor(p, m);
    if (lane == 0) qls[eloc] = p + inb[row];
  }
  __syncthreads();
  const int cl = t & 63, ds = t >> 6;
  float acc = 0.f;
#pragma unroll
  for (int d2 = 0; d2 < 8; ++d2) {
    const int d = ds * 8 + d2;
    acc += W[(size_t)(256 + h * 64 + d) * 256 + qt * 64 + cl] * qls[d];
  }
  red[ds * 64 + cl] = acc;
  __syncthreads();
  if (ds == 0) {
    float s = 0.f;
#pragma unroll
    for (int i = 0; i < 8; ++i) s += red[i * 64 + cl];
    kq[h * 256 + qt * 64 + cl] = s;
  }
  if (qt == 0 && t < 64) {
    float v = qls[t] * inb[256 + h * 64 + t];
#pragma unroll
    for (int m = 1; m < 64; m <<= 1) v += __shfl_xor(v, m);
    if (t == 0) c4[h] = v;
  }
}

// ---- Phase A (blocks 16..143): M2 tile (verified R8/R14) ----
__device__ __forceinline__ void phaseA_m2(const float* __restrict__ W, const float* __restrict__ Wout,
                                          float* __restrict__ M2, float* sh, int b2, int t) {
  float* wout_t = sh;  // [8][64]
  const int tile = b2 >> 1, sub = b2 & 1;
  const int h = tile >> 4, e0 = (tile & 15) * 16 + sub * 8;
  {
    const int e = t >> 6, d = t & 63;
    wout_t[e * 64 + d] = Wout[(size_t)(e0 + e) * 256 + h * 64 + d];
  }
  __syncthreads();
  const int c = t & 255, eh = t >> 8;
  float acc[4] = {0.f, 0.f, 0.f, 0.f};
#pragma unroll 8
  for (int d = 0; d < 64; ++d) {
    const float wv = W[(size_t)(512 + h * 64 + d) * 256 + c];
#pragma unroll
    for (int e = 0; e < 4; ++e) acc[e] += wv * wout_t[(eh * 4 + e) * 64 + d];
  }
#pragma unroll
  for (int e = 0; e < 4; ++e)
    M2[(size_t)(e0 + eh * 4 + e) * 1024 + h * 256 + c] = acc[e];
}

// ---- Phase A (blocks 144..159): bias2[e] = Wout[e].bv + bout[e] (verified R8/R14) ----
__device__ __forceinline__ void phaseA_b2(const float* __restrict__ Wout, const float* __restrict__ inb,
                                          const float* __restrict__ bout, float* __restrict__ bias2,
                                          float* sh, int b, int t) {
  float* red = sh;  // 512
  const int og = t >> 5, seg = t & 31;
  const int e = b * 16 + og;
  float acc = 0.f;
#pragma unroll
  for (int j = 0; j < 8; ++j)
    acc += Wout[(size_t)e * 256 + seg * 8 + j] * inb[512 + seg * 8 + j];
  red[og * 32 + seg] = acc;
  __syncthreads();
  if (t < 16) {
    float s = bout[b * 16 + t];
#pragma unroll
    for (int i = 0; i < 32; ++i) s += red[t * 32 + i];
    bias2[b * 16 + t] = s;
  }
}

// ---- Phase B: verbatim R14 (verified) ----
__device__ __forceinline__ float bscore(float4 xv, float4 kq0, float4 kq1, float4 kq2,
                                        float4 kq3, float c4v, int lane) {
  float p0 = dot4(xv, kq0), p1 = dot4(xv, kq1), p2 = dot4(xv, kq2), p3 = dot4(xv, kq3);
  const bool b1 = (lane & 2) != 0;
  float keep0 = b1 ? p2 : p0, send0 = b1 ? p0 : p2;
  keep0 += __shfl_xor(send0, 2);
  float keep1 = b1 ? p3 : p1, send1 = b1 ? p1 : p3;
  keep1 += __shfl_xor(send1, 2);
  const bool b0 = (lane & 1) != 0;
  float vv = b0 ? keep1 : keep0, sv = b0 ? keep0 : keep1;
  vv += __shfl_xor(sv, 1);
  vv += __shfl_xor(vv, 4);
  vv += __shfl_xor(vv, 8);
  vv += __shfl_xor(vv, 16);
  vv += __shfl_xor(vv, 32);
  return (vv + c4v) * 0.125f;
}

__device__ __forceinline__ void phaseB_core(const float4* xvA, const float4* xvB,
                                            const float* __restrict__ kq, const float* __restrict__ c4,
                                            float* __restrict__ ypart, float* __restrict__ lpart,
                                            float* yls, int bid, int t) {
  float* sll = yls + 8192;  // 32
  const int lane = t & 63, w = t >> 6;
  const int hme = lane & 3;
  const float4 kq0 = *(const float4*)&kq[0 * 256 + lane * 4];
  const float4 kq1 = *(const float4*)&kq[1 * 256 + lane * 4];
  const float4 kq2 = *(const float4*)&kq[2 * 256 + lane * 4];
  const float4 kq3 = *(const float4*)&kq[3 * 256 + lane * 4];
  const float c4v = c4[hme];

  float vA[8], vB[8];
#pragma unroll
  for (int r = 0; r < 8; ++r) vA[r] = bscore(xvA[r], kq0, kq1, kq2, kq3, c4v, lane);
#pragma unroll
  for (int r = 0; r < 8; ++r) vB[r] = bscore(xvB[r], kq0, kq1, kq2, kq3, c4v, lane);

  float l = 0.f;
  float4 a[4];
#pragma unroll
  for (int k = 0; k < 4; ++k) a[k] = (float4){0.f, 0.f, 0.f, 0.f};
#pragma unroll
  for (int r = 0; r < 8; ++r) {
    const float e0 = __expf(vA[r]);
    l += e0;
    const float e1 = __shfl_xor(e0, 1);
    const float e2 = __shfl_xor(e0, 2);
    const float e3 = __shfl_xor(e0, 3);
    a[0].x += e0 * xvA[r].x; a[0].y += e0 * xvA[r].y; a[0].z += e0 * xvA[r].z; a[0].w += e0 * xvA[r].w;
    a[1].x += e1 * xvA[r].x; a[1].y += e1 * xvA[r].y; a[1].z += e1 * xvA[r].z; a[1].w += e1 * xvA[r].w;
    a[2].x += e2 * xvA[r].x; a[2].y += e2 * xvA[r].y; a[2].z += e2 * xvA[r].z; a[2].w += e2 * xvA[r].w;
    a[3].x += e3 * xvA[r].x; a[3].y += e3 * xvA[r].y; a[3].z += e3 * xvA[r].z; a[3].w += e3 * xvA[r].w;
  }
#pragma unroll
  for (int r = 0; r < 8; ++r) {
    const float e0 = __expf(vB[r]);
    l += e0;
    const float e1 = __shfl_xor(e0, 1);
    const float e2 = __shfl_xor(e0, 2);
    const float e3 = __shfl_xor(e0, 3);
    a[0].x += e0 * xvB[r].x; a[0].y += e0 * xvB[r].y; a[0].z += e0 * xvB[r].z; a[0].w += e0 * xvB[r].w;
    a[1].x += e1 * xvB[r].x; a[1].y += e1 * xvB[r].y; a[1].z += e1 * xvB[r].z; a[1].w += e1 * xvB[r].w;
    a[2].x += e2 * xvB[r].x; a[2].y += e2 * xvB[r].y; a[2].z += e2 * xvB[r].z; a[2].w += e2 * xvB[r].w;
    a[3].x += e3 * xvB[r].x; a[3].y += e3 * xvB[r].y; a[3].z += e3 * xvB[r].z; a[3].w += e3 * xvB[r].w;
  }

  __syncthreads();
  if (lane < 4) sll[w * 4 + lane] = l;
#pragma unroll
  for (int k = 0; k < 4; ++k) {
    const int h = hme ^ k;
    *(float4*)&yls[w * 1024 + h * 256 + lane * 4] = a[k];
  }
  __syncthreads();

  if (t < 4) {
    float lb = 0.f;
#pragma unroll
    for (int i = 0; i < 8; ++i) lb += sll[i * 4 + t];
    lpart[t * NBLK + bid] = lb;
  }
  float* yp = &ypart[(size_t)bid * 1024];
#pragma unroll
  for (int o = t; o < 1024; o += 512) {
    float s = 0.f;
#pragma unroll
    for (int i = 0; i < 8; ++i) s += yls[i * 1024 + o];
    yp[o] = s;
  }
}

// ---- Phase CF (16 blocks): z-slice + partial-out + int-atomic combine + elected convert ----
__device__ __forceinline__ void phaseCF(const float* __restrict__ lpart, const float* __restrict__ ypart,
                                        const float* __restrict__ M2, const float* __restrict__ bias2,
                                        float* __restrict__ out, int* __restrict__ out_acc,
                                        int* __restrict__ ticket, float* sh, int bid, int t) {
  float* z = sh;            // 64
  float* zred = sh + 64;    // 512
  float* linv = sh + 576;   // 1
  __shared__ int tk;
  const int lane = t & 63, w = t >> 6;
  const int h = bid >> 2;
  const int base = bid * 64;
  if (w == 0) {  // l-reduce for this block's head
    float s = 0.f;
#pragma unroll
    for (int j = 0; j < 4; ++j) s += lpart[h * 256 + j * 64 + lane];
#pragma unroll
    for (int m = 1; m < 64; m <<= 1) s += __shfl_xor(s, m);
    if (lane == 0) linv[0] = 1.0f / s;
  }
  // z slice: entry i (64), group g (8) sums 32 blocks each (fixed order)
  const int i = t >> 3, g = t & 7;
  {
    float s = 0.f;
#pragma unroll 8
    for (int j = 0; j < 32; ++j) {
      const int b = g * 32 + j;
      s += ypart[(size_t)b * 1024 + base + i];
    }
    zred[i * 8 + g] = s;
  }
  __syncthreads();
  if (t < 64) {
    float tot = 0.f;
#pragma unroll
    for (int gg = 0; gg < 8; ++gg) tot += zred[t * 8 + gg];
    z[t] = tot * linv[0];
  }
  __syncthreads();
  // pout[e] over this slice: e = t>>1, half = t&1 (32 MAC each)
  const int e = t >> 1, half = t & 1;
  const float4* m4 = (const float4*)&M2[(size_t)e * 1024 + base + half * 32];
  const float4* z4 = (const float4*)&z[half * 32];
  float acc = 0.f;
#pragma unroll
  for (int j = 0; j < 8; ++j) acc += dot4(m4[j], z4[j]);
  acc += __shfl_xor(acc, 1);
  if (half == 0) atomicAdd(&out_acc[e * 16], __float2int_rn(acc * SCALE));
  __threadfence();
  __syncthreads();
  if (t == 0)
    tk = __hip_atomic_fetch_add(ticket, 1, __ATOMIC_ACQ_REL, __HIP_MEMORY_SCOPE_AGENT);
  __syncthreads();
  if (tk == 15 && t < 256) {  // last block converts
    int v = __hip_atomic_load(&out_acc[t * 16], __ATOMIC_RELAXED, __HIP_MEMORY_SCOPE_AGENT);
    out[t] = (float)v * INV_SCALE + bias2[t];
  }
}

// ---- Cooperative: flagA (A->B) + ONE grid.sync (B->CF) ----
__global__ void __launch_bounds__(512, 1) mha_coop(const float* __restrict__ x,
                                                   const float* __restrict__ W,
                                                   const float* __restrict__ inb,
                                                   const float* __restrict__ Wout,
                                                   const float* __restrict__ bout,
                                                   float* __restrict__ out,
                                                   float* __restrict__ ws) {
  __shared__ __align__(16) float sh[8224];
  const int t = threadIdx.x, bid = blockIdx.x;
  const int lane = t & 63, w = t >> 6;
  int* flagA = (int*)(ws + WS_FLA);
  int* out_acc = (int*)(ws + WS_ACC);
  int* ticket = (int*)(ws + WS_TK);
  cg::grid_group grid = cg::this_grid();

  const int r0 = bid * 128 + w * 16;
  float4 xvA[8], xvB[8];

  if (bid >= 16) {
#pragma unroll
    for (int r = 0; r < 8; ++r)
      xvA[r] = *(const float4*)&x[(size_t)(r0 + r) * 256 + lane * 4];
#pragma unroll
    for (int r = 0; r < 8; ++r)
      xvB[r] = *(const float4*)&x[(size_t)(r0 + 8 + r) * 256 + lane * 4];
  }

  if (bid < 16) {
    phaseA_kq(x, W, inb, ws + WS_KQ, ws + WS_C4, sh, bid, t);
    set_flag(&flagA[bid], t);
#pragma unroll
    for (int r = 0; r < 8; ++r)
      xvA[r] = *(const float4*)&x[(size_t)(r0 + r) * 256 + lane * 4];
#pragma unroll
    for (int r = 0; r < 8; ++r)
      xvB[r] = *(const float4*)&x[(size_t)(r0 + 8 + r) * 256 + lane * 4];
  } else if (bid < 144) {
    phaseA_m2(W, Wout, ws + WS_M2, sh, bid - 16, t);
  } else if (bid < 160) {
    phaseA_b2(Wout, inb, bout, ws + WS_B2, sh, bid - 144, t);
  } else if (bid == 200) {  // zero accumulators + ticket (pre-sync -> visible to CF)
    for (int j = t; j < 4096; j += 512) out_acc[j] = 0;
    if (t == 0) *ticket = 0;
  }

  poll_flags(flagA, 16, t);
  phaseB_core(xvA, xvB, ws + WS_KQ, ws + WS_C4, ws + WS_YP, ws + WS_LP, sh, bid, t);

  grid.sync();  // the single all-to-all rendezvous

  if (bid == 16 && t < 16) flagA[t] = 0;  // reset for next call
  if (bid < 16)
    phaseCF(ws + WS_LP, ws + WS_YP, ws + WS_M2, ws + WS_B2, out, out_acc, ticket, sh, bid, t);
}

// ---- Fallback chain (no coop): 3 launches ----
__global__ void __launch_bounds__(512) fb_A(const float* __restrict__ x, const float* __restrict__ W,
                                            const float* __restrict__ inb, const float* __restrict__ Wout,
                                            const float* __restrict__ bout, float* __restrict__ ws) {
  __shared__ __align__(16) float sh[832];
  const int bid = blockIdx.x, t = threadIdx.x;
  if (bid < 16) phaseA_kq(x, W, inb, ws + WS_KQ, ws + WS_C4, sh, bid, t);
  else if (bid < 144) phaseA_m2(W, Wout, ws + WS_M2, sh, bid - 16, t);
  else if (bid < 160) phaseA_b2(Wout, inb, bout, ws + WS_B2, sh, bid - 144, t);
  else {
    int* out_acc = (int*)(ws + WS_ACC);
    for (int j = t; j < 4096; j += 512) out_acc[j] = 0;
    if (t == 0) *(int*)(ws + WS_TK) = 0;
  }
}
__global__ void __launch_bounds__(512) fb_B(const float* __restrict__ x, float* __restrict__ ws) {
  __shared__ __align__(16) float sh[8224];
  const int bid = blockIdx.x, t = threadIdx.x;
  const int lane = t & 63, w = t >> 6;
  const int r0 = bid * 128 + w * 16;
  float4 xvA[8], xvB[8];
#pragma unroll
  for (int r = 0; r < 8; ++r)
    xvA[r] = *(const float4*)&x[(size_t)(r0 + r) * 256 + lane * 4];
#pragma unroll
  for (int r = 0; r < 8; ++r)
    xvB[r] = *(const float4*)&x[(size_t)(r0 + 8 + r) * 256 + lane * 4];
  phaseB_core(xvA, xvB, ws + WS_KQ, ws + WS_C4, ws + WS_YP, ws + WS_LP, sh, bid, t);
}
__global__ void __launch_bounds__(512) fb_CF(float* __restrict__ out, float* __restrict__ ws) {
  __shared__ __align__(16) float sh[600];
  phaseCF(ws + WS_LP, ws + WS_YP, ws + WS_M2, ws + WS_B2, out,
          (int*)(ws + WS_ACC), (int*)(ws + WS_TK), sh, blockIdx.x, threadIdx.x);
}

extern "C" void kernel_launch(void* const* d_in, const int* in_sizes, int n_in,
                              void* d_out, int out_size, void* d_ws, size_t ws_size,
                              hipStream_t stream) {
  const float* x = (const float*)d_in[0];
  const float* W = (const float*)d_in[1];
  const float* inb = (const float*)d_in[2];
  const float* Wout = (const float*)d_in[3];
  const float* bout = (const float*)d_in[4];
  float* out = (float*)d_out;
  float* ws = (float*)d_ws;

  int dev = 0;
  (void)hipGetDevice(&dev);
  int coopAttr = 0, ncu = 0, occ = 0;
  bool coop = (hipDeviceGetAttribute(&coopAttr, hipDeviceAttributeCooperativeLaunch, dev) == hipSuccess) &&
              coopAttr != 0;
  coop = coop &&
         (hipDeviceGetAttribute(&ncu, hipDeviceAttributeMultiprocessorCount, dev) == hipSuccess);
  coop = coop &&
         (hipOccupancyMaxActiveBlocksPerMultiprocessor(&occ, mha_coop, 512, 0) == hipSuccess);
  coop = coop && (occ * ncu >= NBLK);

  if (coop) {
    void* args[] = {(void*)&x, (void*)&W, (void*)&inb, (void*)&Wout,
                    (void*)&bout, (void*)&out, (void*)&ws};
    if (hipLaunchCooperativeKernel((const void*)mha_coop, dim3(NBLK), dim3(512),
                                   args, 0, stream) == hipSuccess)
      return;
  }
  fb_A<<<161, 512, 0, stream>>>(x, W, inb, Wout, bout, ws);
  fb_B<<<NBLK, 512, 0, stream>>>(x, ws);
  fb_CF<<<16, 512, 0, stream>>>(out, ws);
}

// Round 17
// 33.867 us; speedup vs baseline: 1.1360x; 1.0138x over previous
//
#include <hip/hip_runtime.h>
#include <hip/hip_cooperative_groups.h>
namespace cg = cooperative_groups;

#define NBLK 272   // 256 B-blocks + 16 A-blocks
#define NB_B 256
// float offsets into ws
#define WS_LP   0        // lpart [4][256]
#define WS_YV   1024     // z = y/l  1024
#define WS_B2   2048     // bias2 256
#define WS_KQ   2304     // kq 1024
#define WS_C4   3328     // c4 4 (pad 64)
#define WS_M2   3392     // M2 256*1024
#define WS_YP   265536   // ypart 256*1024

__device__ __forceinline__ float dot4(float4 a, float4 b) {
  return a.x * b.x + a.y * b.y + a.z * b.z + a.w * b.w;
}

// ---- Phase A (16 dedicated blocks): q_h redundant per (h,qt), kq quarter, c4 (verified R8/R14) ----
__device__ __forceinline__ void phaseA_kq(const float* __restrict__ x, const float* __restrict__ W,
                                          const float* __restrict__ inb, float* __restrict__ kq,
                                          float* __restrict__ c4, float* sh, int ab, int t) {
  float* xs = sh;          // 256
  float* qls = sh + 256;   // 64
  float* red = sh + 320;   // 512
  const int lane = t & 63, w = t >> 6;
  const int h = ab >> 2, qt = ab & 3;
  if (t < 256) xs[t] = x[t];
  __syncthreads();
  const float4 xv = *(const float4*)&xs[lane * 4];
#pragma unroll
  for (int k = 0; k < 8; ++k) {
    const int eloc = w * 8 + k;
    const int row = h * 64 + eloc;
    float4 wv = *(const float4*)&W[(size_t)row * 256 + lane * 4];
    float p = dot4(wv, xv);
#pragma unroll
    for (int m = 1; m < 64; m <<= 1) p += __shfl_xor(p, m);
    if (lane == 0) qls[eloc] = p + inb[row];
  }
  __syncthreads();
  const int cl = t & 63, ds = t >> 6;
  float acc = 0.f;
#pragma unroll
  for (int d2 = 0; d2 < 8; ++d2) {
    const int d = ds * 8 + d2;
    acc += W[(size_t)(256 + h * 64 + d) * 256 + qt * 64 + cl] * qls[d];
  }
  red[ds * 64 + cl] = acc;
  __syncthreads();
  if (ds == 0) {
    float s = 0.f;
#pragma unroll
    for (int i = 0; i < 8; ++i) s += red[i * 64 + cl];
    kq[h * 256 + qt * 64 + cl] = s;
  }
  if (qt == 0 && t < 64) {
    float v = qls[t] * inb[256 + h * 64 + t];
#pragma unroll
    for (int m = 1; m < 64; m <<= 1) v += __shfl_xor(v, m);
    if (t == 0) c4[h] = v;
  }
}

// ---- M2 tile (post-sync2; b2 in 0..127) (verified R8/R14) ----
__device__ __forceinline__ void phaseA_m2(const float* __restrict__ W, const float* __restrict__ Wout,
                                          float* __restrict__ M2, float* sh, int b2, int t) {
  float* wout_t = sh;  // [8][64]
  const int tile = b2 >> 1, sub = b2 & 1;
  const int h = tile >> 4, e0 = (tile & 15) * 16 + sub * 8;
  {
    const int e = t >> 6, d = t & 63;
    wout_t[e * 64 + d] = Wout[(size_t)(e0 + e) * 256 + h * 64 + d];
  }
  __syncthreads();
  const int c = t & 255, eh = t >> 8;
  float acc[4] = {0.f, 0.f, 0.f, 0.f};
#pragma unroll 8
  for (int d = 0; d < 64; ++d) {
    const float wv = W[(size_t)(512 + h * 64 + d) * 256 + c];
#pragma unroll
    for (int e = 0; e < 4; ++e) acc[e] += wv * wout_t[(eh * 4 + e) * 64 + d];
  }
#pragma unroll
  for (int e = 0; e < 4; ++e)
    M2[(size_t)(e0 + eh * 4 + e) * 1024 + h * 256 + c] = acc[e];
}

// ---- bias2[e] = Wout[e].bv + bout[e] (post-sync2; b in 0..15) (verified R8/R14) ----
__device__ __forceinline__ void phaseA_b2(const float* __restrict__ Wout, const float* __restrict__ inb,
                                          const float* __restrict__ bout, float* __restrict__ bias2,
                                          float* sh, int b, int t) {
  float* red = sh;  // 512
  const int og = t >> 5, seg = t & 31;
  const int e = b * 16 + og;
  float acc = 0.f;
#pragma unroll
  for (int j = 0; j < 8; ++j)
    acc += Wout[(size_t)e * 256 + seg * 8 + j] * inb[512 + seg * 8 + j];
  red[og * 32 + seg] = acc;
  __syncthreads();
  if (t < 16) {
    float s = bout[b * 16 + t];
#pragma unroll
    for (int i = 0; i < 32; ++i) s += red[t * 32 + i];
    bias2[b * 16 + t] = s;
  }
}

// ---- Phase B: 16 rows/wave, no max subtraction (verified R13/R14) ----
__device__ __forceinline__ float bscore(float4 xv, float4 kq0, float4 kq1, float4 kq2,
                                        float4 kq3, float c4v, int lane) {
  float p0 = dot4(xv, kq0), p1 = dot4(xv, kq1), p2 = dot4(xv, kq2), p3 = dot4(xv, kq3);
  const bool b1 = (lane & 2) != 0;
  float keep0 = b1 ? p2 : p0, send0 = b1 ? p0 : p2;
  keep0 += __shfl_xor(send0, 2);
  float keep1 = b1 ? p3 : p1, send1 = b1 ? p1 : p3;
  keep1 += __shfl_xor(send1, 2);
  const bool b0 = (lane & 1) != 0;
  float vv = b0 ? keep1 : keep0, sv = b0 ? keep0 : keep1;
  vv += __shfl_xor(sv, 1);
  vv += __shfl_xor(vv, 4);
  vv += __shfl_xor(vv, 8);
  vv += __shfl_xor(vv, 16);
  vv += __shfl_xor(vv, 32);
  return (vv + c4v) * 0.125f;
}

__device__ __forceinline__ void phaseB_core(const float4* xvA, const float4* xvB,
                                            const float* __restrict__ kq, const float* __restrict__ c4,
                                            float* __restrict__ ypart, float* __restrict__ lpart,
                                            float* yls, int bid, int t) {
  float* sll = yls + 8192;  // 32
  const int lane = t & 63, w = t >> 6;
  const int hme = lane & 3;
  const float4 kq0 = *(const float4*)&kq[0 * 256 + lane * 4];
  const float4 kq1 = *(const float4*)&kq[1 * 256 + lane * 4];
  const float4 kq2 = *(const float4*)&kq[2 * 256 + lane * 4];
  const float4 kq3 = *(const float4*)&kq[3 * 256 + lane * 4];
  const float c4v = c4[hme];

  float vA[8], vB[8];
#pragma unroll
  for (int r = 0; r < 8; ++r) vA[r] = bscore(xvA[r], kq0, kq1, kq2, kq3, c4v, lane);
#pragma unroll
  for (int r = 0; r < 8; ++r) vB[r] = bscore(xvB[r], kq0, kq1, kq2, kq3, c4v, lane);

  float l = 0.f;
  float4 a[4];
#pragma unroll
  for (int k = 0; k < 4; ++k) a[k] = (float4){0.f, 0.f, 0.f, 0.f};
#pragma unroll
  for (int r = 0; r < 8; ++r) {
    const float e0 = __expf(vA[r]);
    l += e0;
    const float e1 = __shfl_xor(e0, 1);
    const float e2 = __shfl_xor(e0, 2);
    const float e3 = __shfl_xor(e0, 3);
    a[0].x += e0 * xvA[r].x; a[0].y += e0 * xvA[r].y; a[0].z += e0 * xvA[r].z; a[0].w += e0 * xvA[r].w;
    a[1].x += e1 * xvA[r].x; a[1].y += e1 * xvA[r].y; a[1].z += e1 * xvA[r].z; a[1].w += e1 * xvA[r].w;
    a[2].x += e2 * xvA[r].x; a[2].y += e2 * xvA[r].y; a[2].z += e2 * xvA[r].z; a[2].w += e2 * xvA[r].w;
    a[3].x += e3 * xvA[r].x; a[3].y += e3 * xvA[r].y; a[3].z += e3 * xvA[r].z; a[3].w += e3 * xvA[r].w;
  }
#pragma unroll
  for (int r = 0; r < 8; ++r) {
    const float e0 = __expf(vB[r]);
    l += e0;
    const float e1 = __shfl_xor(e0, 1);
    const float e2 = __shfl_xor(e0, 2);
    const float e3 = __shfl_xor(e0, 3);
    a[0].x += e0 * xvB[r].x; a[0].y += e0 * xvB[r].y; a[0].z += e0 * xvB[r].z; a[0].w += e0 * xvB[r].w;
    a[1].x += e1 * xvB[r].x; a[1].y += e1 * xvB[r].y; a[1].z += e1 * xvB[r].z; a[1].w += e1 * xvB[r].w;
    a[2].x += e2 * xvB[r].x; a[2].y += e2 * xvB[r].y; a[2].z += e2 * xvB[r].z; a[2].w += e2 * xvB[r].w;
    a[3].x += e3 * xvB[r].x; a[3].y += e3 * xvB[r].y; a[3].z += e3 * xvB[r].z; a[3].w += e3 * xvB[r].w;
  }

  __syncthreads();
  if (lane < 4) sll[w * 4 + lane] = l;  // hme==lane for lane<4
#pragma unroll
  for (int k = 0; k < 4; ++k) {
    const int h = hme ^ k;
    *(float4*)&yls[w * 1024 + h * 256 + lane * 4] = a[k];
  }
  __syncthreads();

  if (t < 4) {
    float lb = 0.f;
#pragma unroll
    for (int i = 0; i < 8; ++i) lb += sll[i * 4 + t];
    lpart[t * NB_B + bid] = lb;
  }
  float* yp = &ypart[(size_t)bid * 1024];
#pragma unroll
  for (int o = t; o < 1024; o += 512) {
    float s = 0.f;
#pragma unroll
    for (int i = 0; i < 8; ++i) s += yls[i * 1024 + o];
    yp[o] = s;
  }
}

// ---- Phase C: pure sum reduce + fold 1/l (verified R13/R14). 64 blocks x 16 outputs ----
__device__ __forceinline__ void phaseC(const float* __restrict__ ypart, const float* __restrict__ lpart,
                                       float* __restrict__ z, float* sh, int bid, int t) {
  float* lred = sh;         // 256
  float* sred = sh + 256;   // 512
  const int h = bid >> 4;
  const int o0 = bid * 16;
  if (t < 256) lred[t] = lpart[h * 256 + t];
  __syncthreads();
  for (int s = 128; s > 0; s >>= 1) {
    if (t < s) lred[t] += lred[t + s];
    __syncthreads();
  }
  const float inv = 1.0f / lred[0];
  const int ol = t & 15, bg = t >> 4;  // 32 groups x 8 partial-rows
  float s = 0.f;
#pragma unroll
  for (int j = 0; j < 8; ++j) {
    const int b = bg * 8 + j;
    s += ypart[(size_t)b * 1024 + o0 + ol];
  }
  sred[bg * 16 + ol] = s;
  __syncthreads();
  if (t < 16) {
    float tot = 0.f;
#pragma unroll
    for (int g = 0; g < 32; ++g) tot += sred[g * 16 + t];
    z[o0 + t] = tot * inv;
  }
}

// ---- Phase D: 16 blocks x 16 outputs. out[e] = M2flat[e].z + bias2[e] (verified R13/R14) ----
__device__ __forceinline__ void phaseD(const float* __restrict__ M2, const float* __restrict__ z,
                                       const float* __restrict__ bias2, float* __restrict__ out,
                                       float* sh, int bid, int t) {
  float* zls = sh;          // 1024
  float* smo = sh + 1024;   // 512
  for (int i = t; i < 1024; i += 512) zls[i] = z[i];
  __syncthreads();
  const int og = t >> 5, seg = t & 31;
  const int e = bid * 16 + og;
  float acc = 0.f;
  const float4* m4 = (const float4*)&M2[(size_t)e * 1024 + seg * 32];
  const float4* z4 = (const float4*)&zls[seg * 32];
#pragma unroll
  for (int j = 0; j < 8; ++j) acc += dot4(m4[j], z4[j]);
  smo[og * 32 + seg] = acc;
  __syncthreads();
  if (t < 16) {
    float s = bias2[bid * 16 + t];
#pragma unroll
    for (int i = 0; i < 32; ++i) s += smo[t * 32 + i];
    out[bid * 16 + t] = s;
  }
}

// ---- Cooperative: 272 blocks, 3 grid.syncs, balanced phases ----
__global__ void __launch_bounds__(512, 2) mha_coop(const float* __restrict__ x,
                                                   const float* __restrict__ W,
                                                   const float* __restrict__ inb,
                                                   const float* __restrict__ Wout,
                                                   const float* __restrict__ bout,
                                                   float* __restrict__ out,
                                                   float* __restrict__ ws) {
  __shared__ __align__(16) float sh[8224];
  const int t = threadIdx.x, bid = blockIdx.x;
  const int lane = t & 63, w = t >> 6;
  cg::grid_group grid = cg::this_grid();

  float4 xvA[8], xvB[8];

  if (bid < NB_B) {
    // pure B-block: prefetch immediately (arrives at sync1 ~5.5us)
    const int r0 = bid * 128 + w * 16;
#pragma unroll
    for (int r = 0; r < 8; ++r)
      xvA[r] = *(const float4*)&x[(size_t)(r0 + r) * 256 + lane * 4];
#pragma unroll
    for (int r = 0; r < 8; ++r)
      xvB[r] = *(const float4*)&x[(size_t)(r0 + 8 + r) * 256 + lane * 4];
  } else {
    // dedicated A-block: no B rows, no prefetch
    phaseA_kq(x, W, inb, ws + WS_KQ, ws + WS_C4, sh, bid - NB_B, t);
  }

  grid.sync();  // kq/c4 ready; all B prefetches landed
  if (bid < NB_B)
    phaseB_core(xvA, xvB, ws + WS_KQ, ws + WS_C4, ws + WS_YP, ws + WS_LP, sh, bid, t);
  grid.sync();  // ypart/lpart ready
  if (bid < 64) phaseC(ws + WS_YP, ws + WS_LP, ws + WS_YV, sh, bid, t);
  else if (bid < 192) phaseA_m2(W, Wout, ws + WS_M2, sh, bid - 64, t);
  else if (bid < 208) phaseA_b2(Wout, inb, bout, ws + WS_B2, sh, bid - 192, t);
  grid.sync();  // yv + M2 + bias2 ready
  if (bid < 16) phaseD(ws + WS_M2, ws + WS_YV, ws + WS_B2, out, sh, bid, t);
}

// ---- Fallback chain (no coop): 4 launches, stream-ordered ----
__global__ void __launch_bounds__(512) fb_A(const float* __restrict__ x, const float* __restrict__ W,
                                            const float* __restrict__ inb, float* __restrict__ ws) {
  __shared__ __align__(16) float sh[832];
  phaseA_kq(x, W, inb, ws + WS_KQ, ws + WS_C4, sh, blockIdx.x, threadIdx.x);
}
__global__ void __launch_bounds__(512) fb_B(const float* __restrict__ x, float* __restrict__ ws) {
  __shared__ __align__(16) float sh[8224];
  const int bid = blockIdx.x, t = threadIdx.x;
  const int lane = t & 63, w = t >> 6;
  const int r0 = bid * 128 + w * 16;
  float4 xvA[8], xvB[8];
#pragma unroll
  for (int r = 0; r < 8; ++r)
    xvA[r] = *(const float4*)&x[(size_t)(r0 + r) * 256 + lane * 4];
#pragma unroll
  for (int r = 0; r < 8; ++r)
    xvB[r] = *(const float4*)&x[(size_t)(r0 + 8 + r) * 256 + lane * 4];
  phaseB_core(xvA, xvB, ws + WS_KQ, ws + WS_C4, ws + WS_YP, ws + WS_LP, sh, bid, t);
}
__global__ void __launch_bounds__(512) fb_CM(const float* __restrict__ W, const float* __restrict__ Wout,
                                             const float* __restrict__ inb, const float* __restrict__ bout,
                                             float* __restrict__ ws) {
  __shared__ __align__(16) float sh[832];
  const int bid = blockIdx.x, t = threadIdx.x;
  if (bid < 64) phaseC(ws + WS_YP, ws + WS_LP, ws + WS_YV, sh, bid, t);
  else if (bid < 192) phaseA_m2(W, Wout, ws + WS_M2, sh, bid - 64, t);
  else if (bid < 208) phaseA_b2(Wout, inb, bout, ws + WS_B2, sh, bid - 192, t);
}
__global__ void __launch_bounds__(512) fb_D(float* __restrict__ out, float* __restrict__ ws) {
  __shared__ __align__(16) float sh[1536];
  phaseD(ws + WS_M2, ws + WS_YV, ws + WS_B2, out, sh, blockIdx.x, threadIdx.x);
}

extern "C" void kernel_launch(void* const* d_in, const int* in_sizes, int n_in,
                              void* d_out, int out_size, void* d_ws, size_t ws_size,
                              hipStream_t stream) {
  const float* x = (const float*)d_in[0];
  const float* W = (const float*)d_in[1];
  const float* inb = (const float*)d_in[2];
  const float* Wout = (const float*)d_in[3];
  const float* bout = (const float*)d_in[4];
  float* out = (float*)d_out;
  float* ws = (float*)d_ws;

  int dev = 0;
  (void)hipGetDevice(&dev);
  int coopAttr = 0, ncu = 0, occ = 0;
  bool coop = (hipDeviceGetAttribute(&coopAttr, hipDeviceAttributeCooperativeLaunch, dev) == hipSuccess) &&
              coopAttr != 0;
  coop = coop &&
         (hipDeviceGetAttribute(&ncu, hipDeviceAttributeMultiprocessorCount, dev) == hipSuccess);
  coop = coop &&
         (hipOccupancyMaxActiveBlocksPerMultiprocessor(&occ, mha_coop, 512, 0) == hipSuccess);
  coop = coop && (occ * ncu >= NBLK);

  if (coop) {
    void* args[] = {(void*)&x, (void*)&W, (void*)&inb, (void*)&Wout,
                    (void*)&bout, (void*)&out, (void*)&ws};
    if (hipLaunchCooperativeKernel((const void*)mha_coop, dim3(NBLK), dim3(512),
                                   args, 0, stream) == hipSuccess)
      return;
  }
  fb_A<<<16, 512, 0, stream>>>(x, W, inb, ws);
  fb_B<<<NB_B, 512, 0, stream>>>(x, ws);
  fb_CM<<<208, 512, 0, stream>>>(W, Wout, inb, bout, ws);
  fb_D<<<16, 512, 0, stream>>>(out, ws);
}

// Round 18
// 31.778 us; speedup vs baseline: 1.2106x; 1.0657x over previous
//
#include <hip/hip_runtime.h>
#include <hip/hip_cooperative_groups.h>
namespace cg = cooperative_groups;

#define NBLK 256
// float offsets into ws
#define WS_LP   0        // lpart [4][256]
#define WS_YV   1024     // z = y/l  1024
#define WS_B2   2048     // bias2 256
#define WS_KQ   2304     // kq 1024
#define WS_C4   3328     // c4 4 (pad 64)
#define WS_M2   3392     // M2 256*1024
#define WS_YP   265536   // ypart 256*1024

__device__ __forceinline__ float dot4(float4 a, float4 b) {
  return a.x * b.x + a.y * b.y + a.z * b.z + a.w * b.w;
}

// ---- Phase A distributed over ALL 256 blocks: block b -> kq[h][(b&63)*4 + w] for w<4,
//      h = b>>6. q_h recomputed per block (identical order -> deterministic).
__device__ __forceinline__ void phaseA_dist(const float* __restrict__ x, const float* __restrict__ W,
                                            const float* __restrict__ inb, float* __restrict__ kq,
                                            float* __restrict__ c4, float* qls, int bid, int t) {
  const int lane = t & 63, w = t >> 6;
  const int h = bid >> 6;
  const int c0 = (bid & 63) * 4;
  // q: wave w -> rows h*64 + w*8 .. +7; 8 lanes per row (sub = lane&7 covers 32 elems)
  const int rloc = lane >> 3, sub = lane & 7;
  const int row = h * 64 + w * 8 + rloc;
  const float4* w4 = (const float4*)&W[(size_t)row * 256 + sub * 32];
  const float4* x4 = (const float4*)&x[sub * 32];
  float p = 0.f;
#pragma unroll
  for (int j = 0; j < 8; ++j) p += dot4(w4[j], x4[j]);
  p += __shfl_xor(p, 1);
  p += __shfl_xor(p, 2);
  p += __shfl_xor(p, 4);
  if (sub == 0) qls[w * 8 + rloc] = p + inb[row];
  __syncthreads();
  // kq entries: wave w<4 -> column c0+w; lane = d
  if (w < 4) {
    float v = W[(size_t)(256 + h * 64 + lane) * 256 + (c0 + w)] * qls[lane];
#pragma unroll
    for (int m = 1; m < 64; m <<= 1) v += __shfl_xor(v, m);
    if (lane == 0) kq[h * 256 + c0 + w] = v;
  } else if (w == 4 && (bid & 63) == 0) {
    float v = inb[256 + h * 64 + lane] * qls[lane];
#pragma unroll
    for (int m = 1; m < 64; m <<= 1) v += __shfl_xor(v, m);
    if (lane == 0) c4[h] = v;
  }
}

// ---- M2 tile (C-window; b2 in 0..127) (verified R8/R14) ----
__device__ __forceinline__ void phaseA_m2(const float* __restrict__ W, const float* __restrict__ Wout,
                                          float* __restrict__ M2, float* sh, int b2, int t) {
  float* wout_t = sh;  // [8][64]
  const int tile = b2 >> 1, sub = b2 & 1;
  const int h = tile >> 4, e0 = (tile & 15) * 16 + sub * 8;
  {
    const int e = t >> 6, d = t & 63;
    wout_t[e * 64 + d] = Wout[(size_t)(e0 + e) * 256 + h * 64 + d];
  }
  __syncthreads();
  const int c = t & 255, eh = t >> 8;
  float acc[4] = {0.f, 0.f, 0.f, 0.f};
#pragma unroll 8
  for (int d = 0; d < 64; ++d) {
    const float wv = W[(size_t)(512 + h * 64 + d) * 256 + c];
#pragma unroll
    for (int e = 0; e < 4; ++e) acc[e] += wv * wout_t[(eh * 4 + e) * 64 + d];
  }
#pragma unroll
  for (int e = 0; e < 4; ++e)
    M2[(size_t)(e0 + eh * 4 + e) * 1024 + h * 256 + c] = acc[e];
}

// ---- bias2[e] = Wout[e].bv + bout[e] (C-window; b in 0..15) (verified R8/R14) ----
__device__ __forceinline__ void phaseA_b2(const float* __restrict__ Wout, const float* __restrict__ inb,
                                          const float* __restrict__ bout, float* __restrict__ bias2,
                                          float* sh, int b, int t) {
  float* red = sh;  // 512
  const int og = t >> 5, seg = t & 31;
  const int e = b * 16 + og;
  float acc = 0.f;
#pragma unroll
  for (int j = 0; j < 8; ++j)
    acc += Wout[(size_t)e * 256 + seg * 8 + j] * inb[512 + seg * 8 + j];
  red[og * 32 + seg] = acc;
  __syncthreads();
  if (t < 16) {
    float s = bout[b * 16 + t];
#pragma unroll
    for (int i = 0; i < 32; ++i) s += red[t * 32 + i];
    bias2[b * 16 + t] = s;
  }
}

// ---- Phase B: 16 rows/wave, no max subtraction (verified R13/R14) ----
__device__ __forceinline__ float bscore(float4 xv, float4 kq0, float4 kq1, float4 kq2,
                                        float4 kq3, float c4v, int lane) {
  float p0 = dot4(xv, kq0), p1 = dot4(xv, kq1), p2 = dot4(xv, kq2), p3 = dot4(xv, kq3);
  const bool b1 = (lane & 2) != 0;
  float keep0 = b1 ? p2 : p0, send0 = b1 ? p0 : p2;
  keep0 += __shfl_xor(send0, 2);
  float keep1 = b1 ? p3 : p1, send1 = b1 ? p1 : p3;
  keep1 += __shfl_xor(send1, 2);
  const bool b0 = (lane & 1) != 0;
  float vv = b0 ? keep1 : keep0, sv = b0 ? keep0 : keep1;
  vv += __shfl_xor(sv, 1);
  vv += __shfl_xor(vv, 4);
  vv += __shfl_xor(vv, 8);
  vv += __shfl_xor(vv, 16);
  vv += __shfl_xor(vv, 32);
  return (vv + c4v) * 0.125f;
}

__device__ __forceinline__ void phaseB_core(const float4* xvA, const float4* xvB,
                                            const float* __restrict__ kq, const float* __restrict__ c4,
                                            float* __restrict__ ypart, float* __restrict__ lpart,
                                            float* yls, int bid, int t) {
  float* sll = yls + 8192;  // 32
  const int lane = t & 63, w = t >> 6;
  const int hme = lane & 3;
  const float4 kq0 = *(const float4*)&kq[0 * 256 + lane * 4];
  const float4 kq1 = *(const float4*)&kq[1 * 256 + lane * 4];
  const float4 kq2 = *(const float4*)&kq[2 * 256 + lane * 4];
  const float4 kq3 = *(const float4*)&kq[3 * 256 + lane * 4];
  const float c4v = c4[hme];

  float vA[8], vB[8];
#pragma unroll
  for (int r = 0; r < 8; ++r) vA[r] = bscore(xvA[r], kq0, kq1, kq2, kq3, c4v, lane);
#pragma unroll
  for (int r = 0; r < 8; ++r) vB[r] = bscore(xvB[r], kq0, kq1, kq2, kq3, c4v, lane);

  float l = 0.f;
  float4 a[4];
#pragma unroll
  for (int k = 0; k < 4; ++k) a[k] = (float4){0.f, 0.f, 0.f, 0.f};
#pragma unroll
  for (int r = 0; r < 8; ++r) {
    const float e0 = __expf(vA[r]);
    l += e0;
    const float e1 = __shfl_xor(e0, 1);
    const float e2 = __shfl_xor(e0, 2);
    const float e3 = __shfl_xor(e0, 3);
    a[0].x += e0 * xvA[r].x; a[0].y += e0 * xvA[r].y; a[0].z += e0 * xvA[r].z; a[0].w += e0 * xvA[r].w;
    a[1].x += e1 * xvA[r].x; a[1].y += e1 * xvA[r].y; a[1].z += e1 * xvA[r].z; a[1].w += e1 * xvA[r].w;
    a[2].x += e2 * xvA[r].x; a[2].y += e2 * xvA[r].y; a[2].z += e2 * xvA[r].z; a[2].w += e2 * xvA[r].w;
    a[3].x += e3 * xvA[r].x; a[3].y += e3 * xvA[r].y; a[3].z += e3 * xvA[r].z; a[3].w += e3 * xvA[r].w;
  }
#pragma unroll
  for (int r = 0; r < 8; ++r) {
    const float e0 = __expf(vB[r]);
    l += e0;
    const float e1 = __shfl_xor(e0, 1);
    const float e2 = __shfl_xor(e0, 2);
    const float e3 = __shfl_xor(e0, 3);
    a[0].x += e0 * xvB[r].x; a[0].y += e0 * xvB[r].y; a[0].z += e0 * xvB[r].z; a[0].w += e0 * xvB[r].w;
    a[1].x += e1 * xvB[r].x; a[1].y += e1 * xvB[r].y; a[1].z += e1 * xvB[r].z; a[1].w += e1 * xvB[r].w;
    a[2].x += e2 * xvB[r].x; a[2].y += e2 * xvB[r].y; a[2].z += e2 * xvB[r].z; a[2].w += e2 * xvB[r].w;
    a[3].x += e3 * xvB[r].x; a[3].y += e3 * xvB[r].y; a[3].z += e3 * xvB[r].z; a[3].w += e3 * xvB[r].w;
  }

  __syncthreads();
  if (lane < 4) sll[w * 4 + lane] = l;  // hme==lane for lane<4
#pragma unroll
  for (int k = 0; k < 4; ++k) {
    const int h = hme ^ k;
    *(float4*)&yls[w * 1024 + h * 256 + lane * 4] = a[k];
  }
  __syncthreads();

  if (t < 4) {
    float lb = 0.f;
#pragma unroll
    for (int i = 0; i < 8; ++i) lb += sll[i * 4 + t];
    lpart[t * NBLK + bid] = lb;
  }
  float* yp = &ypart[(size_t)bid * 1024];
#pragma unroll
  for (int o = t; o < 1024; o += 512) {
    float s = 0.f;
#pragma unroll
    for (int i = 0; i < 8; ++i) s += yls[i * 1024 + o];
    yp[o] = s;
  }
}

// ---- Phase C: pure sum reduce + fold 1/l (verified R13/R14). 64 blocks x 16 outputs ----
__device__ __forceinline__ void phaseC(const float* __restrict__ ypart, const float* __restrict__ lpart,
                                       float* __restrict__ z, float* sh, int bid, int t) {
  float* lred = sh;         // 256
  float* sred = sh + 256;   // 512
  const int h = bid >> 4;
  const int o0 = bid * 16;
  if (t < 256) lred[t] = lpart[h * 256 + t];
  __syncthreads();
  for (int s = 128; s > 0; s >>= 1) {
    if (t < s) lred[t] += lred[t + s];
    __syncthreads();
  }
  const float inv = 1.0f / lred[0];
  const int ol = t & 15, bg = t >> 4;  // 32 groups x 8 partial-rows
  float s = 0.f;
#pragma unroll
  for (int j = 0; j < 8; ++j) {
    const int b = bg * 8 + j;
    s += ypart[(size_t)b * 1024 + o0 + ol];
  }
  sred[bg * 16 + ol] = s;
  __syncthreads();
  if (t < 16) {
    float tot = 0.f;
#pragma unroll
    for (int g = 0; g < 32; ++g) tot += sred[g * 16 + t];
    z[o0 + t] = tot * inv;
  }
}

// ---- Phase D: 16 blocks x 16 outputs. out[e] = M2flat[e].z + bias2[e] (verified R13/R14) ----
__device__ __forceinline__ void phaseD(const float* __restrict__ M2, const float* __restrict__ z,
                                       const float* __restrict__ bias2, float* __restrict__ out,
                                       float* sh, int bid, int t) {
  float* zls = sh;          // 1024
  float* smo = sh + 1024;   // 512
  for (int i = t; i < 1024; i += 512) zls[i] = z[i];
  __syncthreads();
  const int og = t >> 5, seg = t & 31;
  const int e = bid * 16 + og;
  float acc = 0.f;
  const float4* m4 = (const float4*)&M2[(size_t)e * 1024 + seg * 32];
  const float4* z4 = (const float4*)&zls[seg * 32];
#pragma unroll
  for (int j = 0; j < 8; ++j) acc += dot4(m4[j], z4[j]);
  smo[og * 32 + seg] = acc;
  __syncthreads();
  if (t < 16) {
    float s = bias2[bid * 16 + t];
#pragma unroll
    for (int i = 0; i < 32; ++i) s += smo[t * 32 + i];
    out[bid * 16 + t] = s;
  }
}

// ---- Cooperative: 256 blocks, 3 grid.syncs, A distributed, no stragglers ----
__global__ void __launch_bounds__(512, 1) mha_coop(const float* __restrict__ x,
                                                   const float* __restrict__ W,
                                                   const float* __restrict__ inb,
                                                   const float* __restrict__ Wout,
                                                   const float* __restrict__ bout,
                                                   float* __restrict__ out,
                                                   float* __restrict__ ws) {
  __shared__ __align__(16) float sh[8224];
  const int t = threadIdx.x, bid = blockIdx.x;
  const int lane = t & 63, w = t >> 6;
  cg::grid_group grid = cg::this_grid();

  // 1) issue this block's x-row prefetch first (everyone, uniformly)
  const int r0 = bid * 128 + w * 16;
  float4 xvA[8], xvB[8];
#pragma unroll
  for (int r = 0; r < 8; ++r)
    xvA[r] = *(const float4*)&x[(size_t)(r0 + r) * 256 + lane * 4];
#pragma unroll
  for (int r = 0; r < 8; ++r)
    xvB[r] = *(const float4*)&x[(size_t)(r0 + 8 + r) * 256 + lane * 4];

  // 2) tiny distributed A-slice (4 kq entries per block)
  phaseA_dist(x, W, inb, ws + WS_KQ, ws + WS_C4, sh, bid, t);

  grid.sync();  // kq/c4 ready; all prefetches landed
  phaseB_core(xvA, xvB, ws + WS_KQ, ws + WS_C4, ws + WS_YP, ws + WS_LP, sh, bid, t);
  grid.sync();  // ypart/lpart ready
  if (bid < 64) phaseC(ws + WS_YP, ws + WS_LP, ws + WS_YV, sh, bid, t);
  else if (bid < 192) phaseA_m2(W, Wout, ws + WS_M2, sh, bid - 64, t);
  else if (bid < 208) phaseA_b2(Wout, inb, bout, ws + WS_B2, sh, bid - 192, t);
  grid.sync();  // yv + M2 + bias2 ready
  if (bid < 16) phaseD(ws + WS_M2, ws + WS_YV, ws + WS_B2, out, sh, bid, t);
}

// ---- Fallback chain (no coop): 4 launches, stream-ordered ----
__global__ void __launch_bounds__(512) fb_A(const float* __restrict__ x, const float* __restrict__ W,
                                            const float* __restrict__ inb, float* __restrict__ ws) {
  __shared__ __align__(16) float sh[64];
  phaseA_dist(x, W, inb, ws + WS_KQ, ws + WS_C4, sh, blockIdx.x, threadIdx.x);
}
__global__ void __launch_bounds__(512) fb_B(const float* __restrict__ x, float* __restrict__ ws) {
  __shared__ __align__(16) float sh[8224];
  const int bid = blockIdx.x, t = threadIdx.x;
  const int lane = t & 63, w = t >> 6;
  const int r0 = bid * 128 + w * 16;
  float4 xvA[8], xvB[8];
#pragma unroll
  for (int r = 0; r < 8; ++r)
    xvA[r] = *(const float4*)&x[(size_t)(r0 + r) * 256 + lane * 4];
#pragma unroll
  for (int r = 0; r < 8; ++r)
    xvB[r] = *(const float4*)&x[(size_t)(r0 + 8 + r) * 256 + lane * 4];
  phaseB_core(xvA, xvB, ws + WS_KQ, ws + WS_C4, ws + WS_YP, ws + WS_LP, sh, bid, t);
}
__global__ void __launch_bounds__(512) fb_CM(const float* __restrict__ W, const float* __restrict__ Wout,
                                             const float* __restrict__ inb, const float* __restrict__ bout,
                                             float* __restrict__ ws) {
  __shared__ __align__(16) float sh[832];
  const int bid = blockIdx.x, t = threadIdx.x;
  if (bid < 64) phaseC(ws + WS_YP, ws + WS_LP, ws + WS_YV, sh, bid, t);
  else if (bid < 192) phaseA_m2(W, Wout, ws + WS_M2, sh, bid - 64, t);
  else if (bid < 208) phaseA_b2(Wout, inb, bout, ws + WS_B2, sh, bid - 192, t);
}
__global__ void __launch_bounds__(512) fb_D(float* __restrict__ out, float* __restrict__ ws) {
  __shared__ __align__(16) float sh[1536];
  phaseD(ws + WS_M2, ws + WS_YV, ws + WS_B2, out, sh, blockIdx.x, threadIdx.x);
}

extern "C" void kernel_launch(void* const* d_in, const int* in_sizes, int n_in,
                              void* d_out, int out_size, void* d_ws, size_t ws_size,
                              hipStream_t stream) {
  const float* x = (const float*)d_in[0];
  const float* W = (const float*)d_in[1];
  const float* inb = (const float*)d_in[2];
  const float* Wout = (const float*)d_in[3];
  const float* bout = (const float*)d_in[4];
  float* out = (float*)d_out;
  float* ws = (float*)d_ws;

  int dev = 0;
  (void)hipGetDevice(&dev);
  int coopAttr = 0, ncu = 0, occ = 0;
  bool coop = (hipDeviceGetAttribute(&coopAttr, hipDeviceAttributeCooperativeLaunch, dev) == hipSuccess) &&
              coopAttr != 0;
  coop = coop &&
         (hipDeviceGetAttribute(&ncu, hipDeviceAttributeMultiprocessorCount, dev) == hipSuccess);
  coop = coop &&
         (hipOccupancyMaxActiveBlocksPerMultiprocessor(&occ, mha_coop, 512, 0) == hipSuccess);
  coop = coop && (occ * ncu >= NBLK);

  if (coop) {
    void* args[] = {(void*)&x, (void*)&W, (void*)&inb, (void*)&Wout,
                    (void*)&bout, (void*)&out, (void*)&ws};
    if (hipLaunchCooperativeKernel((const void*)mha_coop, dim3(NBLK), dim3(512),
                                   args, 0, stream) == hipSuccess)
      return;
  }
  fb_A<<<NBLK, 512, 0, stream>>>(x, W, inb, ws);
  fb_B<<<NBLK, 512, 0, stream>>>(x, ws);
  fb_CM<<<208, 512, 0, stream>>>(W, Wout, inb, bout, ws);
  fb_D<<<16, 512, 0, stream>>>(out, ws);
}